// Round 7
// baseline (348.483 us; speedup 1.0000x reference)
//
#include <hip/hip_runtime.h>

typedef __attribute__((ext_vector_type(8))) short bf16x8;
typedef __attribute__((ext_vector_type(4))) float f32x4;
typedef __attribute__((ext_vector_type(2))) float f32x2;
typedef __attribute__((ext_vector_type(2))) uint u32x2;

static inline size_t align256(size_t x) { return (x + 255) & ~size_t(255); }

__device__ inline ushort f2bf(float f) {
  uint u = __float_as_uint(f);
  return (ushort)((u + 0x7FFFu + ((u >> 16) & 1u)) >> 16);  // RNE
}
__device__ inline float bf2f(ushort h) { return __uint_as_float(((uint)h) << 16); }

#define BW_SHIFT 8            // 256 nodes per bucket
#define NBUCK_MAX 512
#define CHUNK 8192

// ---------------- CSR build: two-phase binned counting sort ----------------

__global__ __launch_bounds__(256) void bucket_hist(const int* __restrict__ row,
                                                   int* __restrict__ bcnt, int E) {
  __shared__ int h[NBUCK_MAX];
  for (int i = threadIdx.x; i < NBUCK_MAX; i += 256) h[i] = 0;
  __syncthreads();
  for (int i = blockIdx.x * 256 + threadIdx.x; i < E; i += gridDim.x * 256)
    atomicAdd(&h[row[i] >> BW_SHIFT], 1);
  __syncthreads();
  for (int i = threadIdx.x; i < NBUCK_MAX; i += 256)
    if (h[i]) atomicAdd(&bcnt[i], h[i]);
}

__global__ __launch_bounds__(NBUCK_MAX) void bucket_scan(const int* __restrict__ bcnt,
                                                         int* __restrict__ boff,
                                                         int* __restrict__ gcur,
                                                         int* __restrict__ offp,
                                                         int E, int n) {
  __shared__ int sh[NBUCK_MAX];
  int t = threadIdx.x;
  int v = bcnt[t];
  sh[t] = v;
  __syncthreads();
  for (int o = 1; o < NBUCK_MAX; o <<= 1) {
    int a = (t >= o) ? sh[t - o] : 0;
    __syncthreads();
    sh[t] += a;
    __syncthreads();
  }
  int excl = sh[t] - v;
  boff[t] = excl;
  gcur[t] = excl;
  if (t == NBUCK_MAX - 1) boff[NBUCK_MAX] = E;
  if (t == 0) offp[n] = E;
}

__global__ __launch_bounds__(256) void bin_scatter(const int* __restrict__ row,
                                                   const int* __restrict__ col,
                                                   const float* __restrict__ w,
                                                   int* __restrict__ gcur,
                                                   int2* __restrict__ es_tmp, int E) {
  __shared__ int lh[NBUCK_MAX];
  __shared__ int lbase[NBUCK_MAX];
  int c0 = blockIdx.x * CHUNK;
  int c1 = min(c0 + CHUNK, E);
  for (int i = threadIdx.x; i < NBUCK_MAX; i += 256) lh[i] = 0;
  __syncthreads();
  for (int i = c0 + threadIdx.x; i < c1; i += 256)
    atomicAdd(&lh[row[i] >> BW_SHIFT], 1);
  __syncthreads();
  for (int i = threadIdx.x; i < NBUCK_MAX; i += 256) {
    int c = lh[i];
    lbase[i] = c ? atomicAdd(&gcur[i], c) : 0;
    lh[i] = 0;
  }
  __syncthreads();
  for (int i = c0 + threadIdx.x; i < c1; i += 256) {
    int r = row[i];
    int b = r >> BW_SHIFT;
    int pos = lbase[b] + atomicAdd(&lh[b], 1);
    es_tmp[pos] = make_int2(((r & 255) << 17) | col[i], __float_as_int(w[i]));
  }
}

// (d) per-bucket node counting-sort. No LDS staging: the bucket (~32 KB) is
// L2-hot on the second read. 2 KB LDS -> high occupancy.
__global__ __launch_bounds__(256) void bucket_sort(const int2* __restrict__ es_tmp,
                                                   const int* __restrict__ boff,
                                                   int2* __restrict__ es,
                                                   int* __restrict__ offp, int n) {
  __shared__ int lh[256];
  __shared__ int lex[256];
  int b = blockIdx.x;
  int base = boff[b], cnt = boff[b + 1] - base;
  int t = threadIdx.x;
  lh[t] = 0;
  __syncthreads();
  for (int i = t; i < cnt; i += 256)
    atomicAdd(&lh[(es_tmp[base + i].x >> 17) & 255], 1);
  __syncthreads();
  int v = lh[t];
  lex[t] = v;
  __syncthreads();
  for (int o = 1; o < 256; o <<= 1) {
    int a = (t >= o) ? lex[t - o] : 0;
    __syncthreads();
    lex[t] += a;
    __syncthreads();
  }
  int excl = lex[t] - v;
  int node = (b << BW_SHIFT) + t;
  if (node < n) offp[node] = base + excl;
  __syncthreads();
  lh[t] = excl;
  __syncthreads();
  for (int i = t; i < cnt; i += 256) {
    int2 ed = es_tmp[base + i];
    int nl = (ed.x >> 17) & 255;
    int pos = base + atomicAdd(&lh[nl], 1);
    es[pos] = make_int2(ed.x & 0x1FFFF, ed.y);
  }
}

// ---------------- W transpose + bf16 convert ----------------

__global__ __launch_bounds__(256) void prep_wt_kernel(const float* __restrict__ W0,
                                                      const float* __restrict__ W1,
                                                      const float* __restrict__ W2,
                                                      ushort* __restrict__ Wt) {
  int i = blockIdx.x * 256 + threadIdx.x;
  if (i >= 3 * 16384) return;
  int mat = i >> 14, r = i & 16383;
  int k = r >> 7, c = r & 127;
  const float* W = (mat == 0) ? W0 : (mat == 1) ? W1 : W2;
  Wt[mat * 16384 + c * 128 + k] = f2bf(W[k * 128 + c]);
}

// ---------------- fused 3x GEMM via MFMA (swapped operands) ----------------

__global__ __launch_bounds__(256) void gemm3_kernel(
    const float* __restrict__ x, const ushort* __restrict__ Wt,
    const float* __restrict__ b0, const float* __restrict__ b1,
    const float* __restrict__ b2,
    float* __restrict__ out0,      // stride 384 (d_out col 0..127)
    ushort* __restrict__ y12,      // bf16 co-located y1|y2, stride 256
    int n) {
  int w = threadIdx.x >> 6;
  int l = threadIdx.x & 63;
  int lr = l & 15;
  int lg = l >> 4;
  int rows0 = blockIdx.x * 256 + w * 64;

  bf16x8 xf[4][4];
#pragma unroll
  for (int rt = 0; rt < 4; ++rt) {
    int row = rows0 + rt * 16 + lr;
    bool ok = row < n;
    const float* base = x + (size_t)row * 128;
#pragma unroll
    for (int kc = 0; kc < 4; ++kc) {
      float4 a = ok ? *(const float4*)(base + kc * 32 + lg * 8) : make_float4(0, 0, 0, 0);
      float4 c = ok ? *(const float4*)(base + kc * 32 + lg * 8 + 4) : make_float4(0, 0, 0, 0);
      bf16x8 f;
      f[0] = (short)f2bf(a.x); f[1] = (short)f2bf(a.y);
      f[2] = (short)f2bf(a.z); f[3] = (short)f2bf(a.w);
      f[4] = (short)f2bf(c.x); f[5] = (short)f2bf(c.y);
      f[6] = (short)f2bf(c.z); f[7] = (short)f2bf(c.w);
      xf[rt][kc] = f;
    }
  }

  for (int mat = 0; mat < 3; ++mat) {
    const ushort* Wm = Wt + mat * 16384;
    const float* bias = (mat == 0) ? b0 : (mat == 1) ? b1 : b2;
#pragma unroll 1
    for (int ct = 0; ct < 8; ++ct) {
      bf16x8 wf[4];
#pragma unroll
      for (int kc = 0; kc < 4; ++kc)
        wf[kc] = *(const bf16x8*)(Wm + (ct * 16 + lr) * 128 + kc * 32 + lg * 8);
      float4 bb = *(const float4*)(bias + ct * 16 + lg * 4);
      f32x4 acc[4];
#pragma unroll
      for (int rt = 0; rt < 4; ++rt) {
        acc[rt][0] = bb.x; acc[rt][1] = bb.y; acc[rt][2] = bb.z; acc[rt][3] = bb.w;
      }
#pragma unroll
      for (int kc = 0; kc < 4; ++kc)
#pragma unroll
        for (int rt = 0; rt < 4; ++rt)
          acc[rt] = __builtin_amdgcn_mfma_f32_16x16x32_bf16(wf[kc], xf[rt][kc], acc[rt], 0, 0, 0);
#pragma unroll
      for (int rt = 0; rt < 4; ++rt) {
        int row = rows0 + rt * 16 + lr;
        if (row >= n) continue;
        int col = ct * 16 + lg * 4;
        if (mat == 0) {
          __builtin_nontemporal_store(acc[rt], (f32x4*)(out0 + (size_t)row * 384 + col));
        } else {
          u32x2 h;
          h.x = (uint)f2bf(acc[rt][0]) | ((uint)f2bf(acc[rt][1]) << 16);
          h.y = (uint)f2bf(acc[rt][2]) | ((uint)f2bf(acc[rt][3]) << 16);
          ushort* Y = y12 + (size_t)row * 256 + ((mat == 2) ? 128 : 0);
          __builtin_nontemporal_store(h, (u32x2*)(Y + col));
        }
      }
    }
  }
}

// ---------------- SpMM (CSR, wave per node, half-wave split) ----------------
// y12 row = 512 B = [y1 row bf16 | y2 row bf16]. Lane l loads u32x2 at byte
// 8*l: one VMEM instruction fetches the whole row. Lanes 0..31 accumulate x1
// (y1 channels 4l..4l+3), lanes 32..63 accumulate z2 (y2 channels 4(l-32)..).

__global__ __launch_bounds__(256) void spmm_dual_kernel(
    const ushort* __restrict__ y12,
    float* __restrict__ o1,        // d_out + 128, stride 384
    ushort* __restrict__ z2,       // bf16, stride 128
    const int* __restrict__ off, const int2* __restrict__ es, int n) {
  int node = blockIdx.x * 4 + (threadIdx.x >> 6);
  if (node >= n) return;
  int l = threadIdx.x & 63;
  int s = off[node], e = off[node + 1];
  float a0 = 0.f, a1 = 0.f, a2 = 0.f, a3 = 0.f;
  int i = s;
  for (; i + 8 <= e; i += 8) {
    u32x2 u[8];
    float w[8];
#pragma unroll
    for (int j = 0; j < 8; ++j) {
      int2 ed = es[i + j];
      w[j] = __int_as_float(ed.y);
      u[j] = *(const u32x2*)(y12 + (size_t)ed.x * 256 + 4 * l);
    }
#pragma unroll
    for (int j = 0; j < 8; ++j) {
      a0 += w[j] * bf2f((ushort)u[j].x); a1 += w[j] * bf2f((ushort)(u[j].x >> 16));
      a2 += w[j] * bf2f((ushort)u[j].y); a3 += w[j] * bf2f((ushort)(u[j].y >> 16));
    }
  }
  for (; i < e; ++i) {
    int2 ed = es[i];
    float w = __int_as_float(ed.y);
    u32x2 u = *(const u32x2*)(y12 + (size_t)ed.x * 256 + 4 * l);
    a0 += w * bf2f((ushort)u.x); a1 += w * bf2f((ushort)(u.x >> 16));
    a2 += w * bf2f((ushort)u.y); a3 += w * bf2f((ushort)(u.y >> 16));
  }
  if (l < 32) {
    f32x4 v; v[0] = a0; v[1] = a1; v[2] = a2; v[3] = a3;
    __builtin_nontemporal_store(v, (f32x4*)(o1 + (size_t)node * 384 + 4 * l));
  } else {
    u32x2 z;
    z.x = (uint)f2bf(a0) | ((uint)f2bf(a1) << 16);
    z.y = (uint)f2bf(a2) | ((uint)f2bf(a3) << 16);
    __builtin_nontemporal_store(z, (u32x2*)(z2 + (size_t)node * 128 + 4 * (l - 32)));
  }
}

// single: x2 = A*z2 (bf16 gather, 256 B row = one dword/lane)
__global__ __launch_bounds__(256) void spmm_single_kernel(
    const ushort* __restrict__ z2,
    float* __restrict__ o2,        // d_out + 256, stride 384
    const int* __restrict__ off, const int2* __restrict__ es, int n) {
  int node = blockIdx.x * 4 + (threadIdx.x >> 6);
  if (node >= n) return;
  int l = threadIdx.x & 63;
  int s = off[node], e = off[node + 1];
  float a0 = 0.f, a1 = 0.f;
  int i = s;
  for (; i + 8 <= e; i += 8) {
    uint u[8];
    float w[8];
#pragma unroll
    for (int j = 0; j < 8; ++j) {
      int2 ed = es[i + j];
      w[j] = __int_as_float(ed.y);
      u[j] = *(const uint*)(z2 + (size_t)ed.x * 128 + 2 * l);
    }
#pragma unroll
    for (int j = 0; j < 8; ++j) {
      a0 += w[j] * bf2f((ushort)u[j]); a1 += w[j] * bf2f((ushort)(u[j] >> 16));
    }
  }
  for (; i < e; ++i) {
    int2 ed = es[i];
    float w = __int_as_float(ed.y);
    uint u = *(const uint*)(z2 + (size_t)ed.x * 128 + 2 * l);
    a0 += w * bf2f((ushort)u); a1 += w * bf2f((ushort)(u >> 16));
  }
  f32x2 v; v.x = a0; v.y = a1;
  __builtin_nontemporal_store(v, (f32x2*)(o2 + (size_t)node * 384 + 2 * l));
}

// ---------------- launch ----------------

extern "C" void kernel_launch(void* const* d_in, const int* in_sizes, int n_in,
                              void* d_out, int out_size, void* d_ws, size_t ws_size,
                              hipStream_t stream) {
  const float* x   = (const float*)d_in[0];
  const int*   row = (const int*)d_in[1];
  const int*   col = (const int*)d_in[2];
  const float* ew  = (const float*)d_in[3];
  const float* W0  = (const float*)d_in[4];
  const float* b0  = (const float*)d_in[5];
  const float* W1  = (const float*)d_in[6];
  const float* b1  = (const float*)d_in[7];
  const float* W2  = (const float*)d_in[8];
  const float* b2  = (const float*)d_in[9];
  float* out = (float*)d_out;

  int n = in_sizes[0] / 128;
  int E = in_sizes[1];

  char* p = (char*)d_ws;
  size_t o = 0;
  ushort* y12 = (ushort*)(p + o); o = align256(o + (size_t)n * 256 * 2);
  ushort* z2  = (ushort*)(p + o); o = align256(o + (size_t)n * 128 * 2);
  ushort* Wt  = (ushort*)(p + o); o = align256(o + (size_t)3 * 16384 * 2);
  int* bcnt   = (int*)(p + o);    o = align256(o + (size_t)NBUCK_MAX * 4);
  int* boff   = (int*)(p + o);    o = align256(o + (size_t)(NBUCK_MAX + 1) * 4);
  int* gcur   = (int*)(p + o);    o = align256(o + (size_t)NBUCK_MAX * 4);
  int* offp   = (int*)(p + o);    o = align256(o + ((size_t)n + 1) * 4);
  int2* es_t  = (int2*)(p + o);   o = align256(o + (size_t)E * 8);
  int2* es    = (int2*)(p + o);   o = align256(o + (size_t)E * 8);
  (void)ws_size; (void)n_in; (void)out_size;

  int nbuck = (n + 255) >> 8;

  // CSR build (binned counting sort)
  hipMemsetAsync(bcnt, 0, (size_t)NBUCK_MAX * 4, stream);
  bucket_hist<<<1024, 256, 0, stream>>>(row, bcnt, E);
  bucket_scan<<<1, NBUCK_MAX, 0, stream>>>(bcnt, boff, gcur, offp, E, n);
  bin_scatter<<<(E + CHUNK - 1) / CHUNK, 256, 0, stream>>>(row, col, ew, gcur, es_t, E);
  bucket_sort<<<nbuck, 256, 0, stream>>>(es_t, boff, es, offp, n);

  // Weights -> bf16 transposed
  prep_wt_kernel<<<192, 256, 0, stream>>>(W0, W1, W2, Wt);

  // Fused GEMMs: out0 fp32, y12 bf16
  gemm3_kernel<<<(n + 255) / 256, 256, 0, stream>>>(x, Wt, b0, b1, b2,
                                                    out, y12, n);

  // x1 -> out[:,128:256], z2 (bf16) -> ws
  spmm_dual_kernel<<<(n + 3) / 4, 256, 0, stream>>>(y12, out + 128, z2,
                                                    offp, es, n);
  // x2 = A*z2 -> out[:,256:384]
  spmm_single_kernel<<<(n + 3) / 4, 256, 0, stream>>>(z2, out + 256,
                                                      offp, es, n);
}

// Round 8
// 308.846 us; speedup vs baseline: 1.1283x; 1.1283x over previous
//
#include <hip/hip_runtime.h>

typedef __attribute__((ext_vector_type(8))) short bf16x8;
typedef __attribute__((ext_vector_type(4))) float f32x4;
typedef __attribute__((ext_vector_type(2))) float f32x2;
typedef __attribute__((ext_vector_type(2))) uint u32x2;
typedef __attribute__((ext_vector_type(4))) uint u32x4;

static inline size_t align256(size_t x) { return (x + 255) & ~size_t(255); }

__device__ inline ushort f2bf(float f) {
  uint u = __float_as_uint(f);
  return (ushort)((u + 0x7FFFu + ((u >> 16) & 1u)) >> 16);  // RNE
}
__device__ inline float bf2f(ushort h) { return __uint_as_float(((uint)h) << 16); }

#define BW_SHIFT 8            // 256 nodes per bucket
#define NBUCK_MAX 512
#define CHUNK 8192

// ---------------- CSR build: two-phase binned counting sort ----------------

__global__ __launch_bounds__(256) void bucket_hist(const int* __restrict__ row,
                                                   int* __restrict__ bcnt, int E) {
  __shared__ int h[NBUCK_MAX];
  for (int i = threadIdx.x; i < NBUCK_MAX; i += 256) h[i] = 0;
  __syncthreads();
  for (int i = blockIdx.x * 256 + threadIdx.x; i < E; i += gridDim.x * 256)
    atomicAdd(&h[row[i] >> BW_SHIFT], 1);
  __syncthreads();
  for (int i = threadIdx.x; i < NBUCK_MAX; i += 256)
    if (h[i]) atomicAdd(&bcnt[i], h[i]);
}

__global__ __launch_bounds__(NBUCK_MAX) void bucket_scan(const int* __restrict__ bcnt,
                                                         int* __restrict__ boff,
                                                         int* __restrict__ gcur,
                                                         int* __restrict__ offp,
                                                         int E, int n) {
  __shared__ int sh[NBUCK_MAX];
  int t = threadIdx.x;
  int v = bcnt[t];
  sh[t] = v;
  __syncthreads();
  for (int o = 1; o < NBUCK_MAX; o <<= 1) {
    int a = (t >= o) ? sh[t - o] : 0;
    __syncthreads();
    sh[t] += a;
    __syncthreads();
  }
  int excl = sh[t] - v;
  boff[t] = excl;
  gcur[t] = excl;
  if (t == NBUCK_MAX - 1) boff[NBUCK_MAX] = E;
  if (t == 0) offp[n] = E;
}

__global__ __launch_bounds__(256) void bin_scatter(const int* __restrict__ row,
                                                   const int* __restrict__ col,
                                                   const float* __restrict__ w,
                                                   int* __restrict__ gcur,
                                                   int2* __restrict__ es_tmp, int E) {
  __shared__ int lh[NBUCK_MAX];
  __shared__ int lbase[NBUCK_MAX];
  int c0 = blockIdx.x * CHUNK;
  int c1 = min(c0 + CHUNK, E);
  for (int i = threadIdx.x; i < NBUCK_MAX; i += 256) lh[i] = 0;
  __syncthreads();
  for (int i = c0 + threadIdx.x; i < c1; i += 256)
    atomicAdd(&lh[row[i] >> BW_SHIFT], 1);
  __syncthreads();
  for (int i = threadIdx.x; i < NBUCK_MAX; i += 256) {
    int c = lh[i];
    lbase[i] = c ? atomicAdd(&gcur[i], c) : 0;
    lh[i] = 0;
  }
  __syncthreads();
  for (int i = c0 + threadIdx.x; i < c1; i += 256) {
    int r = row[i];
    int b = r >> BW_SHIFT;
    int pos = lbase[b] + atomicAdd(&lh[b], 1);
    es_tmp[pos] = make_int2(((r & 255) << 17) | col[i], __float_as_int(w[i]));
  }
}

__global__ __launch_bounds__(256) void bucket_sort(const int2* __restrict__ es_tmp,
                                                   const int* __restrict__ boff,
                                                   int2* __restrict__ es,
                                                   int* __restrict__ offp, int n) {
  __shared__ int lh[256];
  __shared__ int lex[256];
  int b = blockIdx.x;
  int base = boff[b], cnt = boff[b + 1] - base;
  int t = threadIdx.x;
  lh[t] = 0;
  __syncthreads();
  for (int i = t; i < cnt; i += 256)
    atomicAdd(&lh[(es_tmp[base + i].x >> 17) & 255], 1);
  __syncthreads();
  int v = lh[t];
  lex[t] = v;
  __syncthreads();
  for (int o = 1; o < 256; o <<= 1) {
    int a = (t >= o) ? lex[t - o] : 0;
    __syncthreads();
    lex[t] += a;
    __syncthreads();
  }
  int excl = lex[t] - v;
  int node = (b << BW_SHIFT) + t;
  if (node < n) offp[node] = base + excl;
  __syncthreads();
  lh[t] = excl;
  __syncthreads();
  for (int i = t; i < cnt; i += 256) {
    int2 ed = es_tmp[base + i];
    int nl = (ed.x >> 17) & 255;
    int pos = base + atomicAdd(&lh[nl], 1);
    es[pos] = make_int2(ed.x & 0x1FFFF, ed.y);
  }
}

// ---------------- W transpose + bf16 convert ----------------

__global__ __launch_bounds__(256) void prep_wt_kernel(const float* __restrict__ W0,
                                                      const float* __restrict__ W1,
                                                      const float* __restrict__ W2,
                                                      ushort* __restrict__ Wt) {
  int i = blockIdx.x * 256 + threadIdx.x;
  if (i >= 3 * 16384) return;
  int mat = i >> 14, r = i & 16383;
  int k = r >> 7, c = r & 127;
  const float* W = (mat == 0) ? W0 : (mat == 1) ? W1 : W2;
  Wt[mat * 16384 + c * 128 + k] = f2bf(W[k * 128 + c]);
}

// ---------------- fused 3x GEMM via MFMA (swapped operands) ----------------

__global__ __launch_bounds__(256) void gemm3_kernel(
    const float* __restrict__ x, const ushort* __restrict__ Wt,
    const float* __restrict__ b0, const float* __restrict__ b1,
    const float* __restrict__ b2,
    float* __restrict__ out0,      // stride 384 (d_out col 0..127)
    ushort* __restrict__ y12,      // bf16 co-located y1|y2, stride 256
    int n) {
  int w = threadIdx.x >> 6;
  int l = threadIdx.x & 63;
  int lr = l & 15;
  int lg = l >> 4;
  int rows0 = blockIdx.x * 256 + w * 64;

  bf16x8 xf[4][4];
#pragma unroll
  for (int rt = 0; rt < 4; ++rt) {
    int row = rows0 + rt * 16 + lr;
    bool ok = row < n;
    const float* base = x + (size_t)row * 128;
#pragma unroll
    for (int kc = 0; kc < 4; ++kc) {
      float4 a = ok ? *(const float4*)(base + kc * 32 + lg * 8) : make_float4(0, 0, 0, 0);
      float4 c = ok ? *(const float4*)(base + kc * 32 + lg * 8 + 4) : make_float4(0, 0, 0, 0);
      bf16x8 f;
      f[0] = (short)f2bf(a.x); f[1] = (short)f2bf(a.y);
      f[2] = (short)f2bf(a.z); f[3] = (short)f2bf(a.w);
      f[4] = (short)f2bf(c.x); f[5] = (short)f2bf(c.y);
      f[6] = (short)f2bf(c.z); f[7] = (short)f2bf(c.w);
      xf[rt][kc] = f;
    }
  }

  for (int mat = 0; mat < 3; ++mat) {
    const ushort* Wm = Wt + mat * 16384;
    const float* bias = (mat == 0) ? b0 : (mat == 1) ? b1 : b2;
#pragma unroll 1
    for (int ct = 0; ct < 8; ++ct) {
      bf16x8 wf[4];
#pragma unroll
      for (int kc = 0; kc < 4; ++kc)
        wf[kc] = *(const bf16x8*)(Wm + (ct * 16 + lr) * 128 + kc * 32 + lg * 8);
      float4 bb = *(const float4*)(bias + ct * 16 + lg * 4);
      f32x4 acc[4];
#pragma unroll
      for (int rt = 0; rt < 4; ++rt) {
        acc[rt][0] = bb.x; acc[rt][1] = bb.y; acc[rt][2] = bb.z; acc[rt][3] = bb.w;
      }
#pragma unroll
      for (int kc = 0; kc < 4; ++kc)
#pragma unroll
        for (int rt = 0; rt < 4; ++rt)
          acc[rt] = __builtin_amdgcn_mfma_f32_16x16x32_bf16(wf[kc], xf[rt][kc], acc[rt], 0, 0, 0);
#pragma unroll
      for (int rt = 0; rt < 4; ++rt) {
        int row = rows0 + rt * 16 + lr;
        if (row >= n) continue;
        int col = ct * 16 + lg * 4;
        if (mat == 0) {
          // pure output, never re-read -> NT
          __builtin_nontemporal_store(acc[rt], (f32x4*)(out0 + (size_t)row * 384 + col));
        } else {
          // y12 is re-read by spmm_dual -> keep cached (regular store)
          u32x2 h;
          h.x = (uint)f2bf(acc[rt][0]) | ((uint)f2bf(acc[rt][1]) << 16);
          h.y = (uint)f2bf(acc[rt][2]) | ((uint)f2bf(acc[rt][3]) << 16);
          ushort* Y = y12 + (size_t)row * 256 + ((mat == 2) ? 128 : 0);
          *(u32x2*)(Y + col) = h;
        }
      }
    }
  }
}

// ---------------- SpMM (CSR, 2 nodes/wave, 16 B/lane gathers) ----------------
// dual: half-wave (32 lanes) per node. Lane h loads bf16x8 (16 B) covering
// channels 8h..8h+7 of the 512 B y12 row -> one dwordx4 instr per edge
// fetches the whole row. h<16 -> y1 channels (to o1 fp32); h>=16 -> y2
// channels (to z2 bf16).

__global__ __launch_bounds__(256) void spmm_dual_kernel(
    const ushort* __restrict__ y12,
    float* __restrict__ o1,        // d_out + 128, stride 384
    ushort* __restrict__ z2,       // bf16, stride 128 (re-read -> regular store)
    const int* __restrict__ off, const int2* __restrict__ es, int n) {
  int node = blockIdx.x * 8 + ((threadIdx.x >> 6) << 1) + ((threadIdx.x & 63) >> 5);
  if (node >= n) return;
  int h = threadIdx.x & 31;
  int s = off[node], e = off[node + 1];
  float a0 = 0.f, a1 = 0.f, a2 = 0.f, a3 = 0.f;
  float a4 = 0.f, a5 = 0.f, a6 = 0.f, a7 = 0.f;
  int i = s;
  for (; i + 4 <= e; i += 4) {
    bf16x8 v[4];
    float w[4];
#pragma unroll
    for (int j = 0; j < 4; ++j) {
      int2 ed = es[i + j];
      w[j] = __int_as_float(ed.y);
      v[j] = *(const bf16x8*)(y12 + (size_t)ed.x * 256 + h * 8);
    }
#pragma unroll
    for (int j = 0; j < 4; ++j) {
      a0 += w[j] * bf2f((ushort)v[j][0]); a1 += w[j] * bf2f((ushort)v[j][1]);
      a2 += w[j] * bf2f((ushort)v[j][2]); a3 += w[j] * bf2f((ushort)v[j][3]);
      a4 += w[j] * bf2f((ushort)v[j][4]); a5 += w[j] * bf2f((ushort)v[j][5]);
      a6 += w[j] * bf2f((ushort)v[j][6]); a7 += w[j] * bf2f((ushort)v[j][7]);
    }
  }
  for (; i < e; ++i) {
    int2 ed = es[i];
    float w = __int_as_float(ed.y);
    bf16x8 v = *(const bf16x8*)(y12 + (size_t)ed.x * 256 + h * 8);
    a0 += w * bf2f((ushort)v[0]); a1 += w * bf2f((ushort)v[1]);
    a2 += w * bf2f((ushort)v[2]); a3 += w * bf2f((ushort)v[3]);
    a4 += w * bf2f((ushort)v[4]); a5 += w * bf2f((ushort)v[5]);
    a6 += w * bf2f((ushort)v[6]); a7 += w * bf2f((ushort)v[7]);
  }
  if (h < 16) {
    float* dst = o1 + (size_t)node * 384 + h * 8;
    f32x4 lo; lo[0] = a0; lo[1] = a1; lo[2] = a2; lo[3] = a3;
    f32x4 hi; hi[0] = a4; hi[1] = a5; hi[2] = a6; hi[3] = a7;
    __builtin_nontemporal_store(lo, (f32x4*)dst);
    __builtin_nontemporal_store(hi, (f32x4*)(dst + 4));
  } else {
    u32x4 z;
    z.x = (uint)f2bf(a0) | ((uint)f2bf(a1) << 16);
    z.y = (uint)f2bf(a2) | ((uint)f2bf(a3) << 16);
    z.z = (uint)f2bf(a4) | ((uint)f2bf(a5) << 16);
    z.w = (uint)f2bf(a6) | ((uint)f2bf(a7) << 16);
    *(u32x4*)(z2 + (size_t)node * 128 + (h - 16) * 8) = z;
  }
}

// single: x2 = A*z2. Half-wave per node; lane h loads u32x2 (8 B) covering
// channels 4h..4h+3 of the 256 B z2 row.
__global__ __launch_bounds__(256) void spmm_single_kernel(
    const ushort* __restrict__ z2,
    float* __restrict__ o2,        // d_out + 256, stride 384
    const int* __restrict__ off, const int2* __restrict__ es, int n) {
  int node = blockIdx.x * 8 + ((threadIdx.x >> 6) << 1) + ((threadIdx.x & 63) >> 5);
  if (node >= n) return;
  int h = threadIdx.x & 31;
  int s = off[node], e = off[node + 1];
  float a0 = 0.f, a1 = 0.f, a2 = 0.f, a3 = 0.f;
  int i = s;
  for (; i + 4 <= e; i += 4) {
    u32x2 u[4];
    float w[4];
#pragma unroll
    for (int j = 0; j < 4; ++j) {
      int2 ed = es[i + j];
      w[j] = __int_as_float(ed.y);
      u[j] = *(const u32x2*)(z2 + (size_t)ed.x * 128 + h * 4);
    }
#pragma unroll
    for (int j = 0; j < 4; ++j) {
      a0 += w[j] * bf2f((ushort)u[j].x); a1 += w[j] * bf2f((ushort)(u[j].x >> 16));
      a2 += w[j] * bf2f((ushort)u[j].y); a3 += w[j] * bf2f((ushort)(u[j].y >> 16));
    }
  }
  for (; i < e; ++i) {
    int2 ed = es[i];
    float w = __int_as_float(ed.y);
    u32x2 u = *(const u32x2*)(z2 + (size_t)ed.x * 128 + h * 4);
    a0 += w * bf2f((ushort)u.x); a1 += w * bf2f((ushort)(u.x >> 16));
    a2 += w * bf2f((ushort)u.y); a3 += w * bf2f((ushort)(u.y >> 16));
  }
  f32x4 v; v[0] = a0; v[1] = a1; v[2] = a2; v[3] = a3;
  __builtin_nontemporal_store(v, (f32x4*)(o2 + (size_t)node * 384 + h * 4));
}

// ---------------- launch ----------------

extern "C" void kernel_launch(void* const* d_in, const int* in_sizes, int n_in,
                              void* d_out, int out_size, void* d_ws, size_t ws_size,
                              hipStream_t stream) {
  const float* x   = (const float*)d_in[0];
  const int*   row = (const int*)d_in[1];
  const int*   col = (const int*)d_in[2];
  const float* ew  = (const float*)d_in[3];
  const float* W0  = (const float*)d_in[4];
  const float* b0  = (const float*)d_in[5];
  const float* W1  = (const float*)d_in[6];
  const float* b1  = (const float*)d_in[7];
  const float* W2  = (const float*)d_in[8];
  const float* b2  = (const float*)d_in[9];
  float* out = (float*)d_out;

  int n = in_sizes[0] / 128;
  int E = in_sizes[1];

  char* p = (char*)d_ws;
  size_t o = 0;
  ushort* y12 = (ushort*)(p + o); o = align256(o + (size_t)n * 256 * 2);
  ushort* z2  = (ushort*)(p + o); o = align256(o + (size_t)n * 128 * 2);
  ushort* Wt  = (ushort*)(p + o); o = align256(o + (size_t)3 * 16384 * 2);
  int* bcnt   = (int*)(p + o);    o = align256(o + (size_t)NBUCK_MAX * 4);
  int* boff   = (int*)(p + o);    o = align256(o + (size_t)(NBUCK_MAX + 1) * 4);
  int* gcur   = (int*)(p + o);    o = align256(o + (size_t)NBUCK_MAX * 4);
  int* offp   = (int*)(p + o);    o = align256(o + ((size_t)n + 1) * 4);
  int2* es_t  = (int2*)(p + o);   o = align256(o + (size_t)E * 8);
  int2* es    = (int2*)(p + o);   o = align256(o + (size_t)E * 8);
  (void)ws_size; (void)n_in; (void)out_size;

  int nbuck = (n + 255) >> 8;

  // CSR build (binned counting sort)
  hipMemsetAsync(bcnt, 0, (size_t)NBUCK_MAX * 4, stream);
  bucket_hist<<<1024, 256, 0, stream>>>(row, bcnt, E);
  bucket_scan<<<1, NBUCK_MAX, 0, stream>>>(bcnt, boff, gcur, offp, E, n);
  bin_scatter<<<(E + CHUNK - 1) / CHUNK, 256, 0, stream>>>(row, col, ew, gcur, es_t, E);
  bucket_sort<<<nbuck, 256, 0, stream>>>(es_t, boff, es, offp, n);

  // Weights -> bf16 transposed
  prep_wt_kernel<<<192, 256, 0, stream>>>(W0, W1, W2, Wt);

  // Fused GEMMs: out0 fp32 (NT), y12 bf16 (cached)
  gemm3_kernel<<<(n + 255) / 256, 256, 0, stream>>>(x, Wt, b0, b1, b2,
                                                    out, y12, n);

  // x1 -> out[:,128:256] (NT), z2 (bf16, cached) -> ws
  spmm_dual_kernel<<<(n + 7) / 8, 256, 0, stream>>>(y12, out + 128, z2,
                                                    offp, es, n);
  // x2 = A*z2 -> out[:,256:384] (NT)
  spmm_single_kernel<<<(n + 7) / 8, 256, 0, stream>>>(z2, out + 256,
                                                      offp, es, n);
}